// Round 10
// baseline (136.274 us; speedup 1.0000x reference)
//
#include <hip/hip_runtime.h>
#include <math.h>

#define BATCH 2
#define NPTS (64*64*64)       // 262144 points per batch
#define CIN 32
#define COUT 32
#define NF 64
#define NFEAT 10              // degree <= 2 monomials (deg-3 terms ~1e-5 abs)
#define TWO_PI_F 6.283185307179586f

#define NBLK_PER_B 1024           // blocks per batch for K1/K3 (2048 total)
#define NBLK_TOT (BATCH * NBLK_PER_B)
#define PPB (NPTS / NBLK_PER_B)   // 256 points per block
#define NIT (PPB / 32)            // 8 iters, 32 points each (psub 0..31)

#define MROWS (NFEAT * CIN)       // 320

// ws layout (floats)
#define WS_P 0                              // NBLK_TOT * MROWS = 655360 (2.6 MB)
#define WS_M (MROWS * NBLK_TOT)             // BATCH*MROWS = 640
#define WS_G (WS_M + BATCH * MROWS)         // BATCH*NF*2*COUT = 8192
#define WS_V (WS_G + BATCH * NF * 2 * COUT) // BATCH*NFEAT*COUT = 640

typedef float f4 __attribute__((ext_vector_type(4)));

// monomial tables, degree <= 2: {1, x0,x1,x2, x00,x01,x02,x11,x12,x22}
__device__ const int   d_EX0[NFEAT]  = {0,1,0,0,2,1,1,0,0,0};
__device__ const int   d_EX1[NFEAT]  = {0,0,1,0,0,1,0,2,1,0};
__device__ const int   d_EX2[NFEAT]  = {0,0,0,1,0,0,1,0,1,2};
__device__ const float d_MULT[NFEAT] = {1,1,1,1,1,2,2,1,2,1};

__device__ __forceinline__ float red_psub(float v) {
    v += __int_as_float(__builtin_amdgcn_ds_swizzle(__float_as_int(v), 0x201F)); // ^8
    v += __int_as_float(__builtin_amdgcn_ds_swizzle(__float_as_int(v), 0x401F)); // ^16
    v += __shfl_xor(v, 32, 64);                                                  // ^32
    return v;
}

// ---------- DIAGNOSTIC C: pure h-stream, identical address pattern, 6 passes.
// No x, no LDS, no epilogue. Measures this pattern's memory ceiling.
__global__ __launch_bounds__(256) void k1_diagC(const float* __restrict__ h,
                                                float* __restrict__ partial) {
    const int blk = blockIdx.x;            // 2048
    const int t = threadIdx.x;
    const size_t fbase = (size_t)blk * (PPB * 32 / 4);  // f4 units
    const f4* hp = reinterpret_cast<const f4*>(h) + fbase;

    f4 acc = (f4)0.f;
    for (int pass = 0; pass < 6; ++pass) {
#pragma unroll 4
        for (int k = 0; k < NIT; ++k)
            acc += hp[t + 256 * k];
    }
    partial[(size_t)blk * MROWS + t] = acc[0] + acc[1] + acc[2] + acc[3];
}

// ---------- DIAGNOSTIC B: full main loop (xs staging + monomials + 10 f4 FMA),
// 2 passes, epilogue stubbed with a dependent VALU sum (keeps acc live, no DCE).
__global__ __launch_bounds__(256, 5) void k1_diagB(const float* __restrict__ h,
                                                   const float* __restrict__ x,
                                                   float* __restrict__ partial) {
    const int blk = blockIdx.x;            // 2048
    const int b = blk >> 10;
    const int blkin = blk & 1023;
    const int t = threadIdx.x;
    const int q = t & 7;
    const int psub = t >> 3;
    const size_t pbase = (size_t)b * NPTS + (size_t)blkin * PPB;

    __shared__ float xs[PPB * 3];
    float dump = 0.f;

    for (int pass = 0; pass < 2; ++pass) {
        __syncthreads();
        if (t < PPB * 3 / 4)
            reinterpret_cast<f4*>(xs)[t] = reinterpret_cast<const f4*>(x + pbase * 3)[t];
        __syncthreads();

        const f4* hp = reinterpret_cast<const f4*>(h + pbase * 32) + q;
        const float* xp = xs + 3 * psub;

        f4 acc[NFEAT];
#pragma unroll
        for (int f = 0; f < NFEAT; ++f) acc[f] = (f4)0.f;

#pragma unroll 4
        for (int k = 0; k < NIT; ++k) {
            float x0 = xp[96 * k + 0];
            float x1 = xp[96 * k + 1];
            float x2 = xp[96 * k + 2];
            f4 hv = hp[(psub + 32 * k) * 8];
            acc[0] += hv;
            acc[1] = __builtin_elementwise_fma((f4)x0, hv, acc[1]);
            acc[2] = __builtin_elementwise_fma((f4)x1, hv, acc[2]);
            acc[3] = __builtin_elementwise_fma((f4)x2, hv, acc[3]);
            float m;
            m = x0 * x0; acc[4] = __builtin_elementwise_fma((f4)m, hv, acc[4]);
            m = x0 * x1; acc[5] = __builtin_elementwise_fma((f4)m, hv, acc[5]);
            m = x0 * x2; acc[6] = __builtin_elementwise_fma((f4)m, hv, acc[6]);
            m = x1 * x1; acc[7] = __builtin_elementwise_fma((f4)m, hv, acc[7]);
            m = x1 * x2; acc[8] = __builtin_elementwise_fma((f4)m, hv, acc[8]);
            m = x2 * x2; acc[9] = __builtin_elementwise_fma((f4)m, hv, acc[9]);
        }
        // dependent sum: keeps every acc live, ~40 VALU (vs real epilogue's ~120 LDS ops)
        float s = 0.f;
#pragma unroll
        for (int f = 0; f < NFEAT; ++f)
            s += acc[f][0] + acc[f][1] + acc[f][2] + acc[f][3];
        dump += s;
    }
    partial[(size_t)blk * MROWS + t] = dump;   // overwritten by diagA later
}

// ---------- DIAGNOSTIC A == R9 k1, 2 passes (pass 2 recomputes identical
// partials, so feeding k1b from this is correct).
__global__ __launch_bounds__(256, 5) void k1_diagA(const float* __restrict__ h,
                                                   const float* __restrict__ x,
                                                   float* __restrict__ partial) {
    const int blk = blockIdx.x;            // 2048
    const int b = blk >> 10;
    const int blkin = blk & 1023;
    const int t = threadIdx.x;
    const int q = t & 7;
    const int psub = t >> 3;
    const size_t pbase = (size_t)b * NPTS + (size_t)blkin * PPB;

    __shared__ float xs[PPB * 3];
    __shared__ float tile[4][MROWS];

    for (int pass = 0; pass < 2; ++pass) {
        __syncthreads();
        if (t < PPB * 3 / 4)
            reinterpret_cast<f4*>(xs)[t] = reinterpret_cast<const f4*>(x + pbase * 3)[t];
        __syncthreads();

        const f4* hp = reinterpret_cast<const f4*>(h + pbase * 32) + q;
        const float* xp = xs + 3 * psub;

        f4 acc[NFEAT];
#pragma unroll
        for (int f = 0; f < NFEAT; ++f) acc[f] = (f4)0.f;

#pragma unroll 4
        for (int k = 0; k < NIT; ++k) {
            float x0 = xp[96 * k + 0];
            float x1 = xp[96 * k + 1];
            float x2 = xp[96 * k + 2];
            f4 hv = hp[(psub + 32 * k) * 8];
            acc[0] += hv;
            acc[1] = __builtin_elementwise_fma((f4)x0, hv, acc[1]);
            acc[2] = __builtin_elementwise_fma((f4)x1, hv, acc[2]);
            acc[3] = __builtin_elementwise_fma((f4)x2, hv, acc[3]);
            float m;
            m = x0 * x0; acc[4] = __builtin_elementwise_fma((f4)m, hv, acc[4]);
            m = x0 * x1; acc[5] = __builtin_elementwise_fma((f4)m, hv, acc[5]);
            m = x0 * x2; acc[6] = __builtin_elementwise_fma((f4)m, hv, acc[6]);
            m = x1 * x1; acc[7] = __builtin_elementwise_fma((f4)m, hv, acc[7]);
            m = x1 * x2; acc[8] = __builtin_elementwise_fma((f4)m, hv, acc[8]);
            m = x2 * x2; acc[9] = __builtin_elementwise_fma((f4)m, hv, acc[9]);
        }

#pragma unroll
        for (int f = 0; f < NFEAT; ++f) {
#pragma unroll
            for (int e = 0; e < 4; ++e) acc[f][e] = red_psub(acc[f][e]);
        }

        const int w = t >> 6;
        const int lane = t & 63;
        const int i4 = q << 2;
        if (lane < 8) {
#pragma unroll
            for (int f = 0; f < NFEAT; ++f)
                *reinterpret_cast<f4*>(&tile[w][f * CIN + i4]) = acc[f];
        }
        __syncthreads();
        for (int idx = t; idx < MROWS; idx += 256) {
            float s = tile[0][idx] + tile[1][idx] + tile[2][idx] + tile[3][idx];
            partial[(size_t)blk * MROWS + idx] = s;
        }
    }
}

// K1b: M[b][idx] = sum over the 1024 blocks of batch b. 640 blocks. (R9 exact)
__global__ __launch_bounds__(256) void k1b_reduce(const float* __restrict__ partial,
                                                  float* __restrict__ mws) {
    const int r = blockIdx.x;              // 640 = BATCH * MROWS
    const int b = r / MROWS, idx = r % MROWS;
    const int t = threadIdx.x;
    const float* p = partial + (size_t)b * NBLK_PER_B * MROWS + idx;
    float s = p[(size_t)t * MROWS] + p[((size_t)t + 256) * MROWS]
            + p[((size_t)t + 512) * MROWS] + p[((size_t)t + 768) * MROWS];
#pragma unroll
    for (int off = 32; off >= 1; off >>= 1) s += __shfl_down(s, off, 64);
    __shared__ float wsum[4];
    if ((t & 63) == 0) wsum[t >> 6] = s;
    __syncthreads();
    if (t == 0) mws[b * MROWS + idx] = wsum[0] + wsum[1] + wsum[2] + wsum[3];
}

// K2a: per (b,f): H_re/H_im from M, then G = H @ kernel (complex) (R9 exact)
__global__ __launch_bounds__(64) void k2a_HG(const float* __restrict__ mws,
                                             const float* __restrict__ modes,
                                             const float* __restrict__ kre,
                                             const float* __restrict__ kim,
                                             float* __restrict__ gws) {
    const int bf = blockIdx.x;             // 128 = BATCH*NF
    const int b = bf >> 6, f = bf & 63;
    const int t = threadIdx.x;
    const int half = t >> 5;               // 0: re, 1: im
    const int lane = t & 31;

    const float u0 = TWO_PI_F * modes[f * 3 + 0];
    const float u1 = TWO_PI_F * modes[f * 3 + 1];
    const float u2 = TWO_PI_F * modes[f * 3 + 2];

    __shared__ float sH[2][32];
    float hv = 0.f;
#pragma unroll
    for (int fi = 0; fi < NFEAT; ++fi) {
        const int e0 = d_EX0[fi], e1 = d_EX1[fi], e2 = d_EX2[fi];
        const int deg = e0 + e1 + e2;
        float up = d_MULT[fi];
#pragma unroll
        for (int r = 0; r < 2; ++r) { if (r < e0) up *= u0; }
#pragma unroll
        for (int r = 0; r < 2; ++r) { if (r < e1) up *= u1; }
#pragma unroll
        for (int r = 0; r < 2; ++r) { if (r < e2) up *= u2; }
        float cc = (deg == 0) ? 1.f : ((deg == 2) ? -0.5f * up : 0.f);
        float cs = (deg == 1) ? up : 0.f;
        float coef = (half == 0) ? cc : -cs;
        hv = fmaf(coef, mws[b * MROWS + fi * CIN + lane], hv);
    }
    sH[half][lane] = hv;
    __syncthreads();

    float go = 0.f;
#pragma unroll 8
    for (int i2 = 0; i2 < CIN; ++i2) {
        float a = kre[((size_t)f * CIN + i2) * COUT + lane];
        float c = kim[((size_t)f * CIN + i2) * COUT + lane];
        float hre = sH[0][i2], him = sH[1][i2];
        go += (half == 0) ? (hre * a - him * c) : (hre * c + him * a);
    }
    gws[(((size_t)b * NF + f) * 2 + half) * COUT + lane] = go;
}

// K2b: V[b][feat][o] = sum_f ccos*Gre - csin*Gim ; fold in fc_w/fc_b (R9 exact)
__global__ __launch_bounds__(320) void k2b_V(const float* __restrict__ gws,
                                             const float* __restrict__ modes,
                                             const float* __restrict__ fcw,
                                             const float* __restrict__ fcb,
                                             float* __restrict__ vws) {
    const int b = blockIdx.x;              // 2
    const int t = threadIdx.x;             // 320 = 10*32
    const int fi = t >> 5;
    const int o = t & 31;

    const int e0 = d_EX0[fi], e1 = d_EX1[fi], e2 = d_EX2[fi];
    const int deg = e0 + e1 + e2;
    const float mult = d_MULT[fi];

    float acc = 0.f;
    for (int f = 0; f < NF; ++f) {
        float u0 = TWO_PI_F * modes[f * 3 + 0];
        float u1 = TWO_PI_F * modes[f * 3 + 1];
        float u2 = TWO_PI_F * modes[f * 3 + 2];
        float up = mult;
        for (int r = 0; r < e0; ++r) up *= u0;
        for (int r = 0; r < e1; ++r) up *= u1;
        for (int r = 0; r < e2; ++r) up *= u2;
        float cc = (deg == 0) ? 1.f : ((deg == 2) ? -0.5f * up : 0.f);
        float cs = (deg == 1) ? up : 0.f;
        float gre = gws[(((size_t)b * NF + f) * 2 + 0) * COUT + o];
        float gim = gws[(((size_t)b * NF + f) * 2 + 1) * COUT + o];
        acc += cc * gre - cs * gim;
    }
    if (fi == 0) acc += fcb[o];
    else if (deg == 1) acc += fcw[(fi - 1) * COUT + o];
    vws[(b * NFEAT + fi) * COUT + o] = acc;
}

// K3 (R9 exact)
__global__ __launch_bounds__(256, 8) void k3_out(const float* __restrict__ x,
                                                 const float* __restrict__ vws,
                                                 float* __restrict__ out) {
    const int blk = blockIdx.x;            // 2048: 1024 per batch
    const int b = blk >> 10;
    const int blkin = blk & 1023;
    const int t = threadIdx.x;
    const int q = t & 7;
    const int o4 = q << 2;
    const int psub = t >> 3;               // 0..31
    const size_t pbase = (size_t)b * NPTS + (size_t)blkin * PPB;

    __shared__ float xs[PPB * 3];
    if (t < PPB * 3 / 4)
        reinterpret_cast<f4*>(xs)[t] = reinterpret_cast<const f4*>(x + pbase * 3)[t];

    f4 v[NFEAT];
#pragma unroll
    for (int f = 0; f < NFEAT; ++f)
        v[f] = *reinterpret_cast<const f4*>(&vws[(b * NFEAT + f) * COUT + o4]);

    __syncthreads();

    const float KS = -1.702f * 1.4426950408889634f;  // -1.702*log2(e)

#pragma unroll 4
    for (int k = 0; k < NIT; ++k) {
        const int pp = psub + 32 * k;
        float x0 = xs[pp * 3 + 0];
        float x1 = xs[pp * 3 + 1];
        float x2 = xs[pp * 3 + 2];
        f4 y = v[0];
        y = __builtin_elementwise_fma((f4)x0, v[1], y);
        y = __builtin_elementwise_fma((f4)x1, v[2], y);
        y = __builtin_elementwise_fma((f4)x2, v[3], y);
        float m;
        m = x0 * x0; y = __builtin_elementwise_fma((f4)m, v[4], y);
        m = x0 * x1; y = __builtin_elementwise_fma((f4)m, v[5], y);
        m = x0 * x2; y = __builtin_elementwise_fma((f4)m, v[6], y);
        m = x1 * x1; y = __builtin_elementwise_fma((f4)m, v[7], y);
        m = x1 * x2; y = __builtin_elementwise_fma((f4)m, v[8], y);
        m = x2 * x2; y = __builtin_elementwise_fma((f4)m, v[9], y);
        f4 r;
#pragma unroll
        for (int e = 0; e < 4; ++e) {
            float yy = y[e];
            float ex = exp2f(KS * yy);
            r[e] = yy * __builtin_amdgcn_rcpf(1.f + ex);
        }
        __builtin_nontemporal_store(r, reinterpret_cast<f4*>(&out[(pbase + pp) * 32 + o4]));
    }
}

extern "C" void kernel_launch(void* const* d_in, const int* in_sizes, int n_in,
                              void* d_out, int out_size, void* d_ws, size_t ws_size,
                              hipStream_t stream) {
    const float* h     = (const float*)d_in[0];
    const float* x     = (const float*)d_in[1];
    const float* modes = (const float*)d_in[2];
    const float* kre   = (const float*)d_in[3];
    const float* kim   = (const float*)d_in[4];
    const float* fcw   = (const float*)d_in[5];
    const float* fcb   = (const float*)d_in[6];
    float* out = (float*)d_out;
    float* ws  = (float*)d_ws;

    // diagnostics first (their partial writes are garbage, overwritten by diagA)
    k1_diagC<<<NBLK_TOT, 256, 0, stream>>>(h, ws + WS_P);
    k1_diagB<<<NBLK_TOT, 256, 0, stream>>>(h, x, ws + WS_P);
    // diagA produces the real partials (pass 2 == pass 1, deterministic)
    k1_diagA<<<NBLK_TOT, 256, 0, stream>>>(h, x, ws + WS_P);
    k1b_reduce<<<MROWS * BATCH, 256, 0, stream>>>(ws + WS_P, ws + WS_M);
    k2a_HG<<<BATCH * NF, 64, 0, stream>>>(ws + WS_M, modes, kre, kim, ws + WS_G);
    k2b_V<<<BATCH, NFEAT * COUT, 0, stream>>>(ws + WS_G, modes, fcw, fcb, ws + WS_V);
    k3_out<<<NBLK_TOT, 256, 0, stream>>>(x, ws + WS_V, out);
}

// Round 11
// 58.717 us; speedup vs baseline: 2.3209x; 2.3209x over previous
//
#include <hip/hip_runtime.h>
#include <math.h>

#define BATCH 2
#define NPTS (64*64*64)       // 262144 points per batch
#define CIN 32
#define COUT 32
#define NF 64
#define NFEAT 10              // degree <= 2 monomials (deg-3 terms ~1e-5 abs)
#define TWO_PI_F 6.283185307179586f

#define NBLK_PER_B 1024           // blocks per batch for K1/K3 (2048 total)
#define NBLK_TOT (BATCH * NBLK_PER_B)
#define PPB (NPTS / NBLK_PER_B)   // 256 points per block
#define NIT (PPB / 32)            // 8 iters, 32 points each (psub 0..31)

#define MROWS (NFEAT * CIN)       // 320

// ws layout (floats)
#define WS_P 0                              // NBLK_TOT * MROWS = 655360 (2.6 MB)
#define WS_M (MROWS * NBLK_TOT)             // BATCH*MROWS = 640
#define WS_G (WS_M + BATCH * MROWS)         // BATCH*NF*2*COUT = 8192
#define WS_V (WS_G + BATCH * NF * 2 * COUT) // BATCH*NFEAT*COUT = 640

typedef float f4 __attribute__((ext_vector_type(4)));

// monomial tables, degree <= 2: {1, x0,x1,x2, x00,x01,x02,x11,x12,x22}
__device__ const int   d_EX0[NFEAT]  = {0,1,0,0,2,1,1,0,0,0};
__device__ const int   d_EX1[NFEAT]  = {0,0,1,0,0,1,0,2,1,0};
__device__ const int   d_EX2[NFEAT]  = {0,0,0,1,0,0,1,0,1,2};
__device__ const float d_MULT[NFEAT] = {1,1,1,1,1,2,2,1,2,1};

__device__ __forceinline__ float red_psub(float v) {
    v += __int_as_float(__builtin_amdgcn_ds_swizzle(__float_as_int(v), 0x201F)); // ^8
    v += __int_as_float(__builtin_amdgcn_ds_swizzle(__float_as_int(v), 0x401F)); // ^16
    v += __shfl_xor(v, 32, 64);                                                  // ^32
    return v;
}

// K1: partial[blk][idx] = per-block partial of M (idx = feat*CIN+i).
// thread = (psub 0..31, channel-quad 0..7). ALL 8 h-loads (128B/lane) issued
// into named registers BEFORE consumption -> 8 KB/wave in flight (fixes the
// depth-1 pipeline the compiler chose in R9: VGPR was 48 = single hv buffer).
__global__ __launch_bounds__(256) void k1_moments(const float* __restrict__ h,
                                                  const float* __restrict__ x,
                                                  float* __restrict__ partial) {
    const int blk = blockIdx.x;            // 2048: 1024 per batch
    const int b = blk >> 10;
    const int blkin = blk & 1023;
    const int t = threadIdx.x;
    const int q = t & 7;                   // channel quad
    const int psub = t >> 3;               // 0..31
    const size_t pbase = (size_t)b * NPTS + (size_t)blkin * PPB;

    __shared__ float xs[PPB * 3];          // 3 KB
    if (t < PPB * 3 / 4)
        reinterpret_cast<f4*>(xs)[t] = reinterpret_cast<const f4*>(x + pbase * 3)[t];

    const f4* hp = reinterpret_cast<const f4*>(h + pbase * 32) + (size_t)psub * 8 + q;

    // issue all 8 independent 16B loads up front (stride 32 points = 256 f4)
    f4 h0 = hp[0 * 256];
    f4 h1 = hp[1 * 256];
    f4 h2 = hp[2 * 256];
    f4 h3 = hp[3 * 256];
    f4 h4 = hp[4 * 256];
    f4 h5 = hp[5 * 256];
    f4 h6 = hp[6 * 256];
    f4 h7 = hp[7 * 256];

    __syncthreads();                        // xs ready

    f4 acc[NFEAT];
#pragma unroll
    for (int f = 0; f < NFEAT; ++f) acc[f] = (f4)0.f;

    const float* xp = xs + 3 * psub;
#define CONSUME(HV, K)                                                      \
    {                                                                       \
        float x0 = xp[96 * (K) + 0];                                        \
        float x1 = xp[96 * (K) + 1];                                        \
        float x2 = xp[96 * (K) + 2];                                        \
        acc[0] += (HV);                                                     \
        acc[1] = __builtin_elementwise_fma((f4)x0, (HV), acc[1]);           \
        acc[2] = __builtin_elementwise_fma((f4)x1, (HV), acc[2]);           \
        acc[3] = __builtin_elementwise_fma((f4)x2, (HV), acc[3]);           \
        float m;                                                            \
        m = x0 * x0; acc[4] = __builtin_elementwise_fma((f4)m, (HV), acc[4]); \
        m = x0 * x1; acc[5] = __builtin_elementwise_fma((f4)m, (HV), acc[5]); \
        m = x0 * x2; acc[6] = __builtin_elementwise_fma((f4)m, (HV), acc[6]); \
        m = x1 * x1; acc[7] = __builtin_elementwise_fma((f4)m, (HV), acc[7]); \
        m = x1 * x2; acc[8] = __builtin_elementwise_fma((f4)m, (HV), acc[8]); \
        m = x2 * x2; acc[9] = __builtin_elementwise_fma((f4)m, (HV), acc[9]); \
    }
    CONSUME(h0, 0) CONSUME(h1, 1) CONSUME(h2, 2) CONSUME(h3, 3)
    CONSUME(h4, 4) CONSUME(h5, 5) CONSUME(h6, 6) CONSUME(h7, 7)
#undef CONSUME

    // fold the 8 psub slots (lane bits 3,4,5)
#pragma unroll
    for (int f = 0; f < NFEAT; ++f) {
#pragma unroll
        for (int e = 0; e < 4; ++e) acc[f][e] = red_psub(acc[f][e]);
    }

    __shared__ float tile[4][MROWS];   // 5 KB
    const int w = t >> 6;
    const int lane = t & 63;
    const int i4 = q << 2;
    if (lane < 8) {
#pragma unroll
        for (int f = 0; f < NFEAT; ++f)
            *reinterpret_cast<f4*>(&tile[w][f * CIN + i4]) = acc[f];
    }
    __syncthreads();
    for (int idx = t; idx < MROWS; idx += 256) {
        float s = tile[0][idx] + tile[1][idx] + tile[2][idx] + tile[3][idx];
        partial[(size_t)blk * MROWS + idx] = s;   // contiguous 1.28KB per block
    }
}

// K1b: M[b][idx] = sum over the 1024 blocks of batch b. 640 blocks.
__global__ __launch_bounds__(256) void k1b_reduce(const float* __restrict__ partial,
                                                  float* __restrict__ mws) {
    const int r = blockIdx.x;              // 640 = BATCH * MROWS
    const int b = r / MROWS, idx = r % MROWS;
    const int t = threadIdx.x;
    const float* p = partial + (size_t)b * NBLK_PER_B * MROWS + idx;
    float s = p[(size_t)t * MROWS] + p[((size_t)t + 256) * MROWS]
            + p[((size_t)t + 512) * MROWS] + p[((size_t)t + 768) * MROWS];
#pragma unroll
    for (int off = 32; off >= 1; off >>= 1) s += __shfl_down(s, off, 64);
    __shared__ float wsum[4];
    if ((t & 63) == 0) wsum[t >> 6] = s;
    __syncthreads();
    if (t == 0) mws[b * MROWS + idx] = wsum[0] + wsum[1] + wsum[2] + wsum[3];
}

// K2a: per (b,f): H_re/H_im from M, then G = H @ kernel (complex)
__global__ __launch_bounds__(64) void k2a_HG(const float* __restrict__ mws,
                                             const float* __restrict__ modes,
                                             const float* __restrict__ kre,
                                             const float* __restrict__ kim,
                                             float* __restrict__ gws) {
    const int bf = blockIdx.x;             // 128 = BATCH*NF
    const int b = bf >> 6, f = bf & 63;
    const int t = threadIdx.x;
    const int half = t >> 5;               // 0: re, 1: im
    const int lane = t & 31;

    const float u0 = TWO_PI_F * modes[f * 3 + 0];
    const float u1 = TWO_PI_F * modes[f * 3 + 1];
    const float u2 = TWO_PI_F * modes[f * 3 + 2];

    __shared__ float sH[2][32];
    float hv = 0.f;
#pragma unroll
    for (int fi = 0; fi < NFEAT; ++fi) {
        const int e0 = d_EX0[fi], e1 = d_EX1[fi], e2 = d_EX2[fi];
        const int deg = e0 + e1 + e2;
        float up = d_MULT[fi];
#pragma unroll
        for (int r = 0; r < 2; ++r) { if (r < e0) up *= u0; }
#pragma unroll
        for (int r = 0; r < 2; ++r) { if (r < e1) up *= u1; }
#pragma unroll
        for (int r = 0; r < 2; ++r) { if (r < e2) up *= u2; }
        float cc = (deg == 0) ? 1.f : ((deg == 2) ? -0.5f * up : 0.f);
        float cs = (deg == 1) ? up : 0.f;
        float coef = (half == 0) ? cc : -cs;
        hv = fmaf(coef, mws[b * MROWS + fi * CIN + lane], hv);
    }
    sH[half][lane] = hv;
    __syncthreads();

    float go = 0.f;
#pragma unroll 8
    for (int i2 = 0; i2 < CIN; ++i2) {
        float a = kre[((size_t)f * CIN + i2) * COUT + lane];
        float c = kim[((size_t)f * CIN + i2) * COUT + lane];
        float hre = sH[0][i2], him = sH[1][i2];
        go += (half == 0) ? (hre * a - him * c) : (hre * c + him * a);
    }
    gws[(((size_t)b * NF + f) * 2 + half) * COUT + lane] = go;
}

// K2b: V[b][feat][o] = sum_f ccos*Gre - csin*Gim ; fold in fc_w/fc_b
__global__ __launch_bounds__(320) void k2b_V(const float* __restrict__ gws,
                                             const float* __restrict__ modes,
                                             const float* __restrict__ fcw,
                                             const float* __restrict__ fcb,
                                             float* __restrict__ vws) {
    const int b = blockIdx.x;              // 2
    const int t = threadIdx.x;             // 320 = 10*32
    const int fi = t >> 5;
    const int o = t & 31;

    const int e0 = d_EX0[fi], e1 = d_EX1[fi], e2 = d_EX2[fi];
    const int deg = e0 + e1 + e2;
    const float mult = d_MULT[fi];

    float acc = 0.f;
    for (int f = 0; f < NF; ++f) {
        float u0 = TWO_PI_F * modes[f * 3 + 0];
        float u1 = TWO_PI_F * modes[f * 3 + 1];
        float u2 = TWO_PI_F * modes[f * 3 + 2];
        float up = mult;
        for (int r = 0; r < e0; ++r) up *= u0;
        for (int r = 0; r < e1; ++r) up *= u1;
        for (int r = 0; r < e2; ++r) up *= u2;
        float cc = (deg == 0) ? 1.f : ((deg == 2) ? -0.5f * up : 0.f);
        float cs = (deg == 1) ? up : 0.f;
        float gre = gws[(((size_t)b * NF + f) * 2 + 0) * COUT + o];
        float gim = gws[(((size_t)b * NF + f) * 2 + 1) * COUT + o];
        acc += cc * gre - cs * gim;
    }
    if (fi == 0) acc += fcb[o];
    else if (deg == 1) acc += fcw[(fi - 1) * COUT + o];
    vws[(b * NFEAT + fi) * COUT + o] = acc;
}

// K3: out[p][o] = gelu( sum_feat mono(x_p) * V[b][feat][o] )
__global__ __launch_bounds__(256, 8) void k3_out(const float* __restrict__ x,
                                                 const float* __restrict__ vws,
                                                 float* __restrict__ out) {
    const int blk = blockIdx.x;            // 2048: 1024 per batch
    const int b = blk >> 10;
    const int blkin = blk & 1023;
    const int t = threadIdx.x;
    const int q = t & 7;
    const int o4 = q << 2;
    const int psub = t >> 3;               // 0..31
    const size_t pbase = (size_t)b * NPTS + (size_t)blkin * PPB;

    __shared__ float xs[PPB * 3];
    if (t < PPB * 3 / 4)
        reinterpret_cast<f4*>(xs)[t] = reinterpret_cast<const f4*>(x + pbase * 3)[t];

    f4 v[NFEAT];
#pragma unroll
    for (int f = 0; f < NFEAT; ++f)
        v[f] = *reinterpret_cast<const f4*>(&vws[(b * NFEAT + f) * COUT + o4]);

    __syncthreads();

    const float KS = -1.702f * 1.4426950408889634f;  // -1.702*log2(e)

#pragma unroll 4
    for (int k = 0; k < NIT; ++k) {
        const int pp = psub + 32 * k;
        float x0 = xs[pp * 3 + 0];
        float x1 = xs[pp * 3 + 1];
        float x2 = xs[pp * 3 + 2];
        f4 y = v[0];
        y = __builtin_elementwise_fma((f4)x0, v[1], y);
        y = __builtin_elementwise_fma((f4)x1, v[2], y);
        y = __builtin_elementwise_fma((f4)x2, v[3], y);
        float m;
        m = x0 * x0; y = __builtin_elementwise_fma((f4)m, v[4], y);
        m = x0 * x1; y = __builtin_elementwise_fma((f4)m, v[5], y);
        m = x0 * x2; y = __builtin_elementwise_fma((f4)m, v[6], y);
        m = x1 * x1; y = __builtin_elementwise_fma((f4)m, v[7], y);
        m = x1 * x2; y = __builtin_elementwise_fma((f4)m, v[8], y);
        m = x2 * x2; y = __builtin_elementwise_fma((f4)m, v[9], y);
        f4 r;
#pragma unroll
        for (int e = 0; e < 4; ++e) {
            float yy = y[e];
            float ex = exp2f(KS * yy);
            r[e] = yy * __builtin_amdgcn_rcpf(1.f + ex);
        }
        __builtin_nontemporal_store(r, reinterpret_cast<f4*>(&out[(pbase + pp) * 32 + o4]));
    }
}

extern "C" void kernel_launch(void* const* d_in, const int* in_sizes, int n_in,
                              void* d_out, int out_size, void* d_ws, size_t ws_size,
                              hipStream_t stream) {
    const float* h     = (const float*)d_in[0];
    const float* x     = (const float*)d_in[1];
    const float* modes = (const float*)d_in[2];
    const float* kre   = (const float*)d_in[3];
    const float* kim   = (const float*)d_in[4];
    const float* fcw   = (const float*)d_in[5];
    const float* fcb   = (const float*)d_in[6];
    float* out = (float*)d_out;
    float* ws  = (float*)d_ws;

    k1_moments<<<NBLK_TOT, 256, 0, stream>>>(h, x, ws + WS_P);
    k1b_reduce<<<MROWS * BATCH, 256, 0, stream>>>(ws + WS_P, ws + WS_M);
    k2a_HG<<<BATCH * NF, 64, 0, stream>>>(ws + WS_M, modes, kre, kim, ws + WS_G);
    k2b_V<<<BATCH, NFEAT * COUT, 0, stream>>>(ws + WS_G, modes, fcw, fcb, ws + WS_V);
    k3_out<<<NBLK_TOT, 256, 0, stream>>>(x, ws + WS_V, out);
}

// Round 12
// 58.033 us; speedup vs baseline: 2.3482x; 1.0118x over previous
//
#include <hip/hip_runtime.h>
#include <math.h>

#define BATCH 2
#define NPTS (64*64*64)       // 262144 points per batch
#define CIN 32
#define COUT 32
#define NF 64
#define NFEAT 10              // degree <= 2 monomials (deg-3 terms ~1e-5 abs)
#define TWO_PI_F 6.283185307179586f

#define NBLK_PER_B 512            // blocks per batch for K1/K3 (1024 total)
#define NBLK_TOT (BATCH * NBLK_PER_B)
#define PPB (NPTS / NBLK_PER_B)   // 512 points per block
#define NIT (PPB / 32)            // 16 point-iters per thread (psub 0..31)

#define MROWS (NFEAT * CIN)       // 320

// ws layout (floats)
#define WS_P 0                              // NBLK_TOT * MROWS = 327680 (1.3 MB)
#define WS_M (MROWS * NBLK_TOT)             // BATCH*MROWS = 640
#define WS_G (WS_M + BATCH * MROWS)         // BATCH*NF*2*COUT = 8192
#define WS_V (WS_G + BATCH * NF * 2 * COUT) // BATCH*NFEAT*COUT = 640

typedef float f4 __attribute__((ext_vector_type(4)));

// monomial tables, degree <= 2: {1, x0,x1,x2, x00,x01,x02,x11,x12,x22}
__device__ const int   d_EX0[NFEAT]  = {0,1,0,0,2,1,1,0,0,0};
__device__ const int   d_EX1[NFEAT]  = {0,0,1,0,0,1,0,2,1,0};
__device__ const int   d_EX2[NFEAT]  = {0,0,0,1,0,0,1,0,1,2};
__device__ const float d_MULT[NFEAT] = {1,1,1,1,1,2,2,1,2,1};

__device__ __forceinline__ float red_psub(float v) {
    v += __int_as_float(__builtin_amdgcn_ds_swizzle(__float_as_int(v), 0x201F)); // ^8
    v += __int_as_float(__builtin_amdgcn_ds_swizzle(__float_as_int(v), 0x401F)); // ^16
    v += __shfl_xor(v, 32, 64);                                                  // ^32
    return v;
}

// K1: partial[blk][idx] = per-block partial of M (idx = feat*CIN+i).
// thread = (psub 0..31, channel-quad 0..7), 16 points/thread.
// 16 h-loads issued into named regs BEFORE the barrier (16KB/wave in flight);
// sched_barrier(0) forbids the scheduler from sinking them into the consume.
__global__ __launch_bounds__(256) void k1_moments(const float* __restrict__ h,
                                                  const float* __restrict__ x,
                                                  float* __restrict__ partial) {
    const int blk = blockIdx.x;            // 1024: 512 per batch
    const int b = blk >> 9;
    const int blkin = blk & 511;
    const int t = threadIdx.x;
    const int q = t & 7;                   // channel quad
    const int psub = t >> 3;               // 0..31
    const size_t pbase = (size_t)b * NPTS + (size_t)blkin * PPB;

    __shared__ float xs[PPB * 3];          // 6 KB
    for (int idx = t; idx < PPB * 3 / 4; idx += 256)
        reinterpret_cast<f4*>(xs)[idx] = reinterpret_cast<const f4*>(x + pbase * 3)[idx];

    const f4* hp = reinterpret_cast<const f4*>(h + pbase * 32) + (size_t)psub * 8 + q;

    // issue all 16 independent 16B loads up front (stride 32 points = 256 f4)
    f4 hA[8], hB[8];
#pragma unroll
    for (int j = 0; j < 8; ++j) hA[j] = hp[(size_t)j * 256];
#pragma unroll
    for (int j = 0; j < 8; ++j) hB[j] = hp[(size_t)(8 + j) * 256];
    __builtin_amdgcn_sched_barrier(0);      // nothing crosses this point

    __syncthreads();                        // xs ready (also drains h-loads)

    f4 acc[NFEAT];
#pragma unroll
    for (int f = 0; f < NFEAT; ++f) acc[f] = (f4)0.f;

    const float* xp = xs + 3 * psub;
#define CONSUME(HV, K)                                                      \
    {                                                                       \
        float x0 = xp[96 * (K) + 0];                                        \
        float x1 = xp[96 * (K) + 1];                                        \
        float x2 = xp[96 * (K) + 2];                                        \
        acc[0] += (HV);                                                     \
        acc[1] = __builtin_elementwise_fma((f4)x0, (HV), acc[1]);           \
        acc[2] = __builtin_elementwise_fma((f4)x1, (HV), acc[2]);           \
        acc[3] = __builtin_elementwise_fma((f4)x2, (HV), acc[3]);           \
        float m;                                                            \
        m = x0 * x0; acc[4] = __builtin_elementwise_fma((f4)m, (HV), acc[4]); \
        m = x0 * x1; acc[5] = __builtin_elementwise_fma((f4)m, (HV), acc[5]); \
        m = x0 * x2; acc[6] = __builtin_elementwise_fma((f4)m, (HV), acc[6]); \
        m = x1 * x1; acc[7] = __builtin_elementwise_fma((f4)m, (HV), acc[7]); \
        m = x1 * x2; acc[8] = __builtin_elementwise_fma((f4)m, (HV), acc[8]); \
        m = x2 * x2; acc[9] = __builtin_elementwise_fma((f4)m, (HV), acc[9]); \
    }
#pragma unroll
    for (int j = 0; j < 8; ++j) CONSUME(hA[j], j)
#pragma unroll
    for (int j = 0; j < 8; ++j) CONSUME(hB[j], 8 + j)
#undef CONSUME

    // fold the 8 psub slots (lane bits 3,4,5)
#pragma unroll
    for (int f = 0; f < NFEAT; ++f) {
#pragma unroll
        for (int e = 0; e < 4; ++e) acc[f][e] = red_psub(acc[f][e]);
    }

    __shared__ float tile[4][MROWS];   // 5 KB
    const int w = t >> 6;
    const int lane = t & 63;
    const int i4 = q << 2;
    if (lane < 8) {
#pragma unroll
        for (int f = 0; f < NFEAT; ++f)
            *reinterpret_cast<f4*>(&tile[w][f * CIN + i4]) = acc[f];
    }
    __syncthreads();
    for (int idx = t; idx < MROWS; idx += 256) {
        float s = tile[0][idx] + tile[1][idx] + tile[2][idx] + tile[3][idx];
        partial[(size_t)blk * MROWS + idx] = s;   // contiguous 1.28KB per block
    }
}

// K1b: M[b][idx] = sum over the 512 blocks of batch b. 640 blocks.
__global__ __launch_bounds__(256) void k1b_reduce(const float* __restrict__ partial,
                                                  float* __restrict__ mws) {
    const int r = blockIdx.x;              // 640 = BATCH * MROWS
    const int b = r / MROWS, idx = r % MROWS;
    const int t = threadIdx.x;
    const float* p = partial + (size_t)b * NBLK_PER_B * MROWS + idx;
    float s = p[(size_t)t * MROWS] + p[((size_t)t + 256) * MROWS];
#pragma unroll
    for (int off = 32; off >= 1; off >>= 1) s += __shfl_down(s, off, 64);
    __shared__ float wsum[4];
    if ((t & 63) == 0) wsum[t >> 6] = s;
    __syncthreads();
    if (t == 0) mws[b * MROWS + idx] = wsum[0] + wsum[1] + wsum[2] + wsum[3];
}

// K2a: per (b,f): H_re/H_im from M, then G = H @ kernel (complex)
__global__ __launch_bounds__(64) void k2a_HG(const float* __restrict__ mws,
                                             const float* __restrict__ modes,
                                             const float* __restrict__ kre,
                                             const float* __restrict__ kim,
                                             float* __restrict__ gws) {
    const int bf = blockIdx.x;             // 128 = BATCH*NF
    const int b = bf >> 6, f = bf & 63;
    const int t = threadIdx.x;
    const int half = t >> 5;               // 0: re, 1: im
    const int lane = t & 31;

    const float u0 = TWO_PI_F * modes[f * 3 + 0];
    const float u1 = TWO_PI_F * modes[f * 3 + 1];
    const float u2 = TWO_PI_F * modes[f * 3 + 2];

    __shared__ float sH[2][32];
    float hv = 0.f;
#pragma unroll
    for (int fi = 0; fi < NFEAT; ++fi) {
        const int e0 = d_EX0[fi], e1 = d_EX1[fi], e2 = d_EX2[fi];
        const int deg = e0 + e1 + e2;
        float up = d_MULT[fi];
#pragma unroll
        for (int r = 0; r < 2; ++r) { if (r < e0) up *= u0; }
#pragma unroll
        for (int r = 0; r < 2; ++r) { if (r < e1) up *= u1; }
#pragma unroll
        for (int r = 0; r < 2; ++r) { if (r < e2) up *= u2; }
        float cc = (deg == 0) ? 1.f : ((deg == 2) ? -0.5f * up : 0.f);
        float cs = (deg == 1) ? up : 0.f;
        float coef = (half == 0) ? cc : -cs;
        hv = fmaf(coef, mws[b * MROWS + fi * CIN + lane], hv);
    }
    sH[half][lane] = hv;
    __syncthreads();

    float go = 0.f;
#pragma unroll 8
    for (int i2 = 0; i2 < CIN; ++i2) {
        float a = kre[((size_t)f * CIN + i2) * COUT + lane];
        float c = kim[((size_t)f * CIN + i2) * COUT + lane];
        float hre = sH[0][i2], him = sH[1][i2];
        go += (half == 0) ? (hre * a - him * c) : (hre * c + him * a);
    }
    gws[(((size_t)b * NF + f) * 2 + half) * COUT + lane] = go;
}

// K2b: V[b][feat][o] = sum_f ccos*Gre - csin*Gim ; fold in fc_w/fc_b
__global__ __launch_bounds__(320) void k2b_V(const float* __restrict__ gws,
                                             const float* __restrict__ modes,
                                             const float* __restrict__ fcw,
                                             const float* __restrict__ fcb,
                                             float* __restrict__ vws) {
    const int b = blockIdx.x;              // 2
    const int t = threadIdx.x;             // 320 = 10*32
    const int fi = t >> 5;
    const int o = t & 31;

    const int e0 = d_EX0[fi], e1 = d_EX1[fi], e2 = d_EX2[fi];
    const int deg = e0 + e1 + e2;
    const float mult = d_MULT[fi];

    float acc = 0.f;
    for (int f = 0; f < NF; ++f) {
        float u0 = TWO_PI_F * modes[f * 3 + 0];
        float u1 = TWO_PI_F * modes[f * 3 + 1];
        float u2 = TWO_PI_F * modes[f * 3 + 2];
        float up = mult;
        for (int r = 0; r < e0; ++r) up *= u0;
        for (int r = 0; r < e1; ++r) up *= u1;
        for (int r = 0; r < e2; ++r) up *= u2;
        float cc = (deg == 0) ? 1.f : ((deg == 2) ? -0.5f * up : 0.f);
        float cs = (deg == 1) ? up : 0.f;
        float gre = gws[(((size_t)b * NF + f) * 2 + 0) * COUT + o];
        float gim = gws[(((size_t)b * NF + f) * 2 + 1) * COUT + o];
        acc += cc * gre - cs * gim;
    }
    if (fi == 0) acc += fcb[o];
    else if (deg == 1) acc += fcw[(fi - 1) * COUT + o];
    vws[(b * NFEAT + fi) * COUT + o] = acc;
}

// K3: out[p][o] = gelu( sum_feat mono(x_p) * V[b][feat][o] )
__global__ __launch_bounds__(256, 8) void k3_out(const float* __restrict__ x,
                                                 const float* __restrict__ vws,
                                                 float* __restrict__ out) {
    const int blk = blockIdx.x;            // 1024: 512 per batch
    const int b = blk >> 9;
    const int blkin = blk & 511;
    const int t = threadIdx.x;
    const int q = t & 7;
    const int o4 = q << 2;
    const int psub = t >> 3;               // 0..31
    const size_t pbase = (size_t)b * NPTS + (size_t)blkin * PPB;

    __shared__ float xs[PPB * 3];          // 6 KB
    for (int idx = t; idx < PPB * 3 / 4; idx += 256)
        reinterpret_cast<f4*>(xs)[idx] = reinterpret_cast<const f4*>(x + pbase * 3)[idx];

    f4 v[NFEAT];
#pragma unroll
    for (int f = 0; f < NFEAT; ++f)
        v[f] = *reinterpret_cast<const f4*>(&vws[(b * NFEAT + f) * COUT + o4]);

    __syncthreads();

    const float KS = -1.702f * 1.4426950408889634f;  // -1.702*log2(e)

#pragma unroll 4
    for (int k = 0; k < NIT; ++k) {
        const int pp = psub + 32 * k;
        float x0 = xs[pp * 3 + 0];
        float x1 = xs[pp * 3 + 1];
        float x2 = xs[pp * 3 + 2];
        f4 y = v[0];
        y = __builtin_elementwise_fma((f4)x0, v[1], y);
        y = __builtin_elementwise_fma((f4)x1, v[2], y);
        y = __builtin_elementwise_fma((f4)x2, v[3], y);
        float m;
        m = x0 * x0; y = __builtin_elementwise_fma((f4)m, v[4], y);
        m = x0 * x1; y = __builtin_elementwise_fma((f4)m, v[5], y);
        m = x0 * x2; y = __builtin_elementwise_fma((f4)m, v[6], y);
        m = x1 * x1; y = __builtin_elementwise_fma((f4)m, v[7], y);
        m = x1 * x2; y = __builtin_elementwise_fma((f4)m, v[8], y);
        m = x2 * x2; y = __builtin_elementwise_fma((f4)m, v[9], y);
        f4 r;
#pragma unroll
        for (int e = 0; e < 4; ++e) {
            float yy = y[e];
            float ex = exp2f(KS * yy);
            r[e] = yy * __builtin_amdgcn_rcpf(1.f + ex);
        }
        __builtin_nontemporal_store(r, reinterpret_cast<f4*>(&out[(pbase + pp) * 32 + o4]));
    }
}

extern "C" void kernel_launch(void* const* d_in, const int* in_sizes, int n_in,
                              void* d_out, int out_size, void* d_ws, size_t ws_size,
                              hipStream_t stream) {
    const float* h     = (const float*)d_in[0];
    const float* x     = (const float*)d_in[1];
    const float* modes = (const float*)d_in[2];
    const float* kre   = (const float*)d_in[3];
    const float* kim   = (const float*)d_in[4];
    const float* fcw   = (const float*)d_in[5];
    const float* fcb   = (const float*)d_in[6];
    float* out = (float*)d_out;
    float* ws  = (float*)d_ws;

    k1_moments<<<NBLK_TOT, 256, 0, stream>>>(h, x, ws + WS_P);
    k1b_reduce<<<MROWS * BATCH, 256, 0, stream>>>(ws + WS_P, ws + WS_M);
    k2a_HG<<<BATCH * NF, 64, 0, stream>>>(ws + WS_M, modes, kre, kim, ws + WS_G);
    k2b_V<<<BATCH, NFEAT * COUT, 0, stream>>>(ws + WS_G, modes, fcw, fcb, ws + WS_V);
    k3_out<<<NBLK_TOT, 256, 0, stream>>>(x, ws + WS_V, out);
}

// Round 13
// 55.566 us; speedup vs baseline: 2.4525x; 1.0444x over previous
//
#include <hip/hip_runtime.h>
#include <math.h>

#define BATCH 2
#define NPTS (64*64*64)       // 262144 points per batch
#define CIN 32
#define COUT 32
#define NF 64
#define NFEAT 10              // degree <= 2 monomials (deg-3 terms ~1e-5 abs)
#define TWO_PI_F 6.283185307179586f

#define NBLK_PER_B 512            // blocks per batch for K1/K3 (1024 total)
#define NBLK_TOT (BATCH * NBLK_PER_B)
#define PPB (NPTS / NBLK_PER_B)   // 512 points per block

#define MROWS (NFEAT * CIN)       // 320

// ws layout (floats)
#define WS_P 0                              // NBLK_TOT * MROWS = 327680 (1.3 MB)
#define WS_M (MROWS * NBLK_TOT)             // BATCH*MROWS = 640
#define WS_G (WS_M + BATCH * MROWS)         // BATCH*NF*2*COUT = 8192
#define WS_V (WS_G + BATCH * NF * 2 * COUT) // BATCH*NFEAT*COUT = 640

typedef float f4 __attribute__((ext_vector_type(4)));

// monomial tables, degree <= 2: {1, x0,x1,x2, x00,x01,x02,x11,x12,x22}
__device__ const int   d_EX0[NFEAT]  = {0,1,0,0,2,1,1,0,0,0};
__device__ const int   d_EX1[NFEAT]  = {0,0,1,0,0,1,0,2,1,0};
__device__ const int   d_EX2[NFEAT]  = {0,0,0,1,0,0,1,0,1,2};
__device__ const float d_MULT[NFEAT] = {1,1,1,1,1,2,2,1,2,1};

__device__ __forceinline__ float red_psub(float v) {
    v += __int_as_float(__builtin_amdgcn_ds_swizzle(__float_as_int(v), 0x201F)); // ^8
    v += __int_as_float(__builtin_amdgcn_ds_swizzle(__float_as_int(v), 0x401F)); // ^16
    v += __shfl_xor(v, 32, 64);                                                  // ^32
    return v;
}

// K1: partial[blk][idx] = per-block partial of M (idx = feat*CIN+i).
// thread = (psub 0..31, channel-quad q 0..7) owns 16 CONTIGUOUS points.
// ZERO LDS in main path: x (48 floats) and h (16 x float4) live in registers,
// all loads issued up front -> continuous load stream, no ds_read latency chain,
// no staging barrier. (diagC proved this address-stream runs ~6 TB/s; the LDS
// path was the 3.7 TB/s limiter.)
__global__ __launch_bounds__(256) void k1_moments(const float* __restrict__ h,
                                                  const float* __restrict__ x,
                                                  float* __restrict__ partial) {
    const int blk = blockIdx.x;            // 1024: 512 per batch
    const int b = blk >> 9;
    const int blkin = blk & 511;
    const int t = threadIdx.x;
    const int q = t & 7;                   // channel quad
    const int psub = t >> 3;               // 0..31
    const size_t p0 = (size_t)b * NPTS + (size_t)blkin * PPB + (size_t)psub * 16;

    const f4* xv = reinterpret_cast<const f4*>(x + p0 * 3);       // 12 f4, 16B-aligned
    const f4* hp = reinterpret_cast<const f4*>(h + p0 * 32) + q;  // point j at [j*8]

    f4 X[12];
#pragma unroll
    for (int j = 0; j < 12; ++j) X[j] = xv[j];
    f4 H[16];
#pragma unroll
    for (int j = 0; j < 16; ++j) H[j] = hp[(size_t)j * 8];

    f4 acc[NFEAT];
#pragma unroll
    for (int f = 0; f < NFEAT; ++f) acc[f] = (f4)0.f;

#pragma unroll
    for (int j = 0; j < 16; ++j) {                // all indices compile-time
        const int e = 3 * j;
        float x0 = X[e >> 2][e & 3];
        float x1 = X[(e + 1) >> 2][(e + 1) & 3];
        float x2 = X[(e + 2) >> 2][(e + 2) & 3];
        f4 hv = H[j];
        acc[0] += hv;
        acc[1] = __builtin_elementwise_fma((f4)x0, hv, acc[1]);
        acc[2] = __builtin_elementwise_fma((f4)x1, hv, acc[2]);
        acc[3] = __builtin_elementwise_fma((f4)x2, hv, acc[3]);
        float m;
        m = x0 * x0; acc[4] = __builtin_elementwise_fma((f4)m, hv, acc[4]);
        m = x0 * x1; acc[5] = __builtin_elementwise_fma((f4)m, hv, acc[5]);
        m = x0 * x2; acc[6] = __builtin_elementwise_fma((f4)m, hv, acc[6]);
        m = x1 * x1; acc[7] = __builtin_elementwise_fma((f4)m, hv, acc[7]);
        m = x1 * x2; acc[8] = __builtin_elementwise_fma((f4)m, hv, acc[8]);
        m = x2 * x2; acc[9] = __builtin_elementwise_fma((f4)m, hv, acc[9]);
    }

    // fold the psub slots sharing this q (lane bits 3,4,5) — proven ~free (R10)
#pragma unroll
    for (int f = 0; f < NFEAT; ++f) {
#pragma unroll
        for (int e = 0; e < 4; ++e) acc[f][e] = red_psub(acc[f][e]);
    }

    __shared__ float tile[4][MROWS];   // 5 KB
    const int w = t >> 6;
    const int lane = t & 63;
    const int i4 = q << 2;
    if (lane < 8) {
#pragma unroll
        for (int f = 0; f < NFEAT; ++f)
            *reinterpret_cast<f4*>(&tile[w][f * CIN + i4]) = acc[f];
    }
    __syncthreads();
    for (int idx = t; idx < MROWS; idx += 256) {
        float s = tile[0][idx] + tile[1][idx] + tile[2][idx] + tile[3][idx];
        partial[(size_t)blk * MROWS + idx] = s;   // contiguous 1.28KB per block
    }
}

// K1b: M[b][idx] = sum over the 512 blocks of batch b. 640 blocks.
__global__ __launch_bounds__(256) void k1b_reduce(const float* __restrict__ partial,
                                                  float* __restrict__ mws) {
    const int r = blockIdx.x;              // 640 = BATCH * MROWS
    const int b = r / MROWS, idx = r % MROWS;
    const int t = threadIdx.x;
    const float* p = partial + (size_t)b * NBLK_PER_B * MROWS + idx;
    float s = p[(size_t)t * MROWS] + p[((size_t)t + 256) * MROWS];
#pragma unroll
    for (int off = 32; off >= 1; off >>= 1) s += __shfl_down(s, off, 64);
    __shared__ float wsum[4];
    if ((t & 63) == 0) wsum[t >> 6] = s;
    __syncthreads();
    if (t == 0) mws[b * MROWS + idx] = wsum[0] + wsum[1] + wsum[2] + wsum[3];
}

// K2a: per (b,f): H_re/H_im from M, then G = H @ kernel (complex)
__global__ __launch_bounds__(64) void k2a_HG(const float* __restrict__ mws,
                                             const float* __restrict__ modes,
                                             const float* __restrict__ kre,
                                             const float* __restrict__ kim,
                                             float* __restrict__ gws) {
    const int bf = blockIdx.x;             // 128 = BATCH*NF
    const int b = bf >> 6, f = bf & 63;
    const int t = threadIdx.x;
    const int half = t >> 5;               // 0: re, 1: im
    const int lane = t & 31;

    const float u0 = TWO_PI_F * modes[f * 3 + 0];
    const float u1 = TWO_PI_F * modes[f * 3 + 1];
    const float u2 = TWO_PI_F * modes[f * 3 + 2];

    __shared__ float sH[2][32];
    float hv = 0.f;
#pragma unroll
    for (int fi = 0; fi < NFEAT; ++fi) {
        const int e0 = d_EX0[fi], e1 = d_EX1[fi], e2 = d_EX2[fi];
        const int deg = e0 + e1 + e2;
        float up = d_MULT[fi];
#pragma unroll
        for (int r = 0; r < 2; ++r) { if (r < e0) up *= u0; }
#pragma unroll
        for (int r = 0; r < 2; ++r) { if (r < e1) up *= u1; }
#pragma unroll
        for (int r = 0; r < 2; ++r) { if (r < e2) up *= u2; }
        float cc = (deg == 0) ? 1.f : ((deg == 2) ? -0.5f * up : 0.f);
        float cs = (deg == 1) ? up : 0.f;
        float coef = (half == 0) ? cc : -cs;
        hv = fmaf(coef, mws[b * MROWS + fi * CIN + lane], hv);
    }
    sH[half][lane] = hv;
    __syncthreads();

    float go = 0.f;
#pragma unroll 8
    for (int i2 = 0; i2 < CIN; ++i2) {
        float a = kre[((size_t)f * CIN + i2) * COUT + lane];
        float c = kim[((size_t)f * CIN + i2) * COUT + lane];
        float hre = sH[0][i2], him = sH[1][i2];
        go += (half == 0) ? (hre * a - him * c) : (hre * c + him * a);
    }
    gws[(((size_t)b * NF + f) * 2 + half) * COUT + lane] = go;
}

// K2b: V[b][feat][o] = sum_f ccos*Gre - csin*Gim ; fold in fc_w/fc_b
__global__ __launch_bounds__(320) void k2b_V(const float* __restrict__ gws,
                                             const float* __restrict__ modes,
                                             const float* __restrict__ fcw,
                                             const float* __restrict__ fcb,
                                             float* __restrict__ vws) {
    const int b = blockIdx.x;              // 2
    const int t = threadIdx.x;             // 320 = 10*32
    const int fi = t >> 5;
    const int o = t & 31;

    const int e0 = d_EX0[fi], e1 = d_EX1[fi], e2 = d_EX2[fi];
    const int deg = e0 + e1 + e2;
    const float mult = d_MULT[fi];

    float acc = 0.f;
    for (int f = 0; f < NF; ++f) {
        float u0 = TWO_PI_F * modes[f * 3 + 0];
        float u1 = TWO_PI_F * modes[f * 3 + 1];
        float u2 = TWO_PI_F * modes[f * 3 + 2];
        float up = mult;
        for (int r = 0; r < e0; ++r) up *= u0;
        for (int r = 0; r < e1; ++r) up *= u1;
        for (int r = 0; r < e2; ++r) up *= u2;
        float cc = (deg == 0) ? 1.f : ((deg == 2) ? -0.5f * up : 0.f);
        float cs = (deg == 1) ? up : 0.f;
        float gre = gws[(((size_t)b * NF + f) * 2 + 0) * COUT + o];
        float gim = gws[(((size_t)b * NF + f) * 2 + 1) * COUT + o];
        acc += cc * gre - cs * gim;
    }
    if (fi == 0) acc += fcb[o];
    else if (deg == 1) acc += fcw[(fi - 1) * COUT + o];
    vws[(b * NFEAT + fi) * COUT + o] = acc;
}

// K3: out[p][o] = gelu( sum_feat mono(x_p) * V[b][feat][o] )
// thread = (psub, channel-quad) owns 16 CONTIGUOUS points; x fully in registers
// (no LDS, no barrier); nontemporal float4 stores.
__global__ __launch_bounds__(256) void k3_out(const float* __restrict__ x,
                                              const float* __restrict__ vws,
                                              float* __restrict__ out) {
    const int blk = blockIdx.x;            // 1024: 512 per batch
    const int b = blk >> 9;
    const int blkin = blk & 511;
    const int t = threadIdx.x;
    const int q = t & 7;
    const int o4 = q << 2;
    const int psub = t >> 3;               // 0..31
    const size_t p0 = (size_t)b * NPTS + (size_t)blkin * PPB + (size_t)psub * 16;

    const f4* xv = reinterpret_cast<const f4*>(x + p0 * 3);

    f4 v[NFEAT];
#pragma unroll
    for (int f = 0; f < NFEAT; ++f)
        v[f] = *reinterpret_cast<const f4*>(&vws[(b * NFEAT + f) * COUT + o4]);

    f4 X[12];
#pragma unroll
    for (int j = 0; j < 12; ++j) X[j] = xv[j];

    const float KS = -1.702f * 1.4426950408889634f;  // -1.702*log2(e)

#pragma unroll
    for (int j = 0; j < 16; ++j) {
        const int e = 3 * j;
        float x0 = X[e >> 2][e & 3];
        float x1 = X[(e + 1) >> 2][(e + 1) & 3];
        float x2 = X[(e + 2) >> 2][(e + 2) & 3];
        f4 y = v[0];
        y = __builtin_elementwise_fma((f4)x0, v[1], y);
        y = __builtin_elementwise_fma((f4)x1, v[2], y);
        y = __builtin_elementwise_fma((f4)x2, v[3], y);
        float m;
        m = x0 * x0; y = __builtin_elementwise_fma((f4)m, v[4], y);
        m = x0 * x1; y = __builtin_elementwise_fma((f4)m, v[5], y);
        m = x0 * x2; y = __builtin_elementwise_fma((f4)m, v[6], y);
        m = x1 * x1; y = __builtin_elementwise_fma((f4)m, v[7], y);
        m = x1 * x2; y = __builtin_elementwise_fma((f4)m, v[8], y);
        m = x2 * x2; y = __builtin_elementwise_fma((f4)m, v[9], y);
        f4 r;
#pragma unroll
        for (int ee = 0; ee < 4; ++ee) {
            float yy = y[ee];
            float ex = exp2f(KS * yy);
            r[ee] = yy * __builtin_amdgcn_rcpf(1.f + ex);
        }
        __builtin_nontemporal_store(r, reinterpret_cast<f4*>(&out[(p0 + j) * 32 + o4]));
    }
}

extern "C" void kernel_launch(void* const* d_in, const int* in_sizes, int n_in,
                              void* d_out, int out_size, void* d_ws, size_t ws_size,
                              hipStream_t stream) {
    const float* h     = (const float*)d_in[0];
    const float* x     = (const float*)d_in[1];
    const float* modes = (const float*)d_in[2];
    const float* kre   = (const float*)d_in[3];
    const float* kim   = (const float*)d_in[4];
    const float* fcw   = (const float*)d_in[5];
    const float* fcb   = (const float*)d_in[6];
    float* out = (float*)d_out;
    float* ws  = (float*)d_ws;

    k1_moments<<<NBLK_TOT, 256, 0, stream>>>(h, x, ws + WS_P);
    k1b_reduce<<<MROWS * BATCH, 256, 0, stream>>>(ws + WS_P, ws + WS_M);
    k2a_HG<<<BATCH * NF, 64, 0, stream>>>(ws + WS_M, modes, kre, kim, ws + WS_G);
    k2b_V<<<BATCH, NFEAT * COUT, 0, stream>>>(ws + WS_G, modes, fcw, fcb, ws + WS_V);
    k3_out<<<NBLK_TOT, 256, 0, stream>>>(x, ws + WS_V, out);
}